// Round 7
// baseline (409.015 us; speedup 1.0000x reference)
//
#include <hip/hip_runtime.h>

#define C_NUM   256
#define K_CODES 4096
#define D_CB    8
#define THREADS 512
#define TPW     8                   // tuples per wave
#define CHUNKS  32                  // per wave: 2048 codes / 64 lanes

__device__ __forceinline__ float rfl(float v) {
    return __int_as_float(__builtin_amdgcn_readfirstlane(__float_as_int(v)));
}

__global__ __launch_bounds__(THREADS, 8)
void dkvb_kernel(const float* __restrict__ emb,
                 const float* __restrict__ keys,
                 const float* __restrict__ values,
                 float* __restrict__ out) {
    __shared__ float xs[32][D_CB];   // 1 KB
    __shared__ float dL[8][TPW];
    __shared__ int   iL[8][TPW];

    const int bid  = blockIdx.x;
    const int c    = bid & 255;      // codebook (grid 1024: 4 blocks/codebook, same XCD)
    const int q    = bid >> 8;       // tuple quarter: tuples q*32 .. q*32+31
    const int tid  = threadIdx.x;
    const int wave = tid >> 6;
    const int lane = tid & 63;
    const int s    = wave & 3;       // tuple slice (8 tuples)
    const int g    = wave >> 2;      // code half: 0 -> 0..2047, 1 -> 2048..4095

    // ---- stage this block's 32 tuples of x into LDS ----
    // x[t][j] = emb[(t>>4)*32768 + c*128 + j*16 + (t&15)]
    if (tid < 256) {
        const int tl = tid >> 3, j = tid & 7;
        const int tg = q * 32 + tl;
        xs[tl][j] = emb[(size_t)(tg >> 4) * 32768 + c * 128 + j * 16 + (tg & 15)];
    }
    __syncthreads();

    // ---- x' = -2*x into SGPRs (wave-uniform, exact scale) ----
    float x[TPW][8];
    #pragma unroll
    for (int t = 0; t < TPW; ++t) {
        #pragma unroll
        for (int j = 0; j < 8; ++j) x[t][j] = rfl(-2.0f * xs[s * TPW + t][j]);
    }

    float bestd[TPW];
    int   besti[TPW];
    #pragma unroll
    for (int t = 0; t < TPW; ++t) { bestd[t] = 3.4028235e38f; besti[t] = 0; }

    // ---- scan this group's 2048 codes; dist' = k2 + sum x'_j k_j ----
    const float4* kb = (const float4*)(keys + (size_t)c * K_CODES * D_CB);
    const int basef4 = g * 4096;     // float4 index of code-half base
    float4 a0 = kb[basef4 + lane * 2];
    float4 a1 = kb[basef4 + lane * 2 + 1];
    for (int ch = 0; ch < CHUNKS; ++ch) {
        const int nc = (ch + 1 < CHUNKS) ? (ch + 1) : ch;
        const float4 b0 = kb[basef4 + nc * 128 + lane * 2];
        const float4 b1 = kb[basef4 + nc * 128 + lane * 2 + 1];

        const int code = g * 2048 + ch * 64 + lane;
        float k2 = a0.x * a0.x;
        k2 = fmaf(a0.y, a0.y, k2);
        k2 = fmaf(a0.z, a0.z, k2);
        k2 = fmaf(a0.w, a0.w, k2);
        k2 = fmaf(a1.x, a1.x, k2);
        k2 = fmaf(a1.y, a1.y, k2);
        k2 = fmaf(a1.z, a1.z, k2);
        k2 = fmaf(a1.w, a1.w, k2);

        #pragma unroll
        for (int t = 0; t < TPW; ++t) {
            float dist = fmaf(x[t][0], a0.x, k2);
            dist = fmaf(x[t][1], a0.y, dist);
            dist = fmaf(x[t][2], a0.z, dist);
            dist = fmaf(x[t][3], a0.w, dist);
            dist = fmaf(x[t][4], a1.x, dist);
            dist = fmaf(x[t][5], a1.y, dist);
            dist = fmaf(x[t][6], a1.z, dist);
            dist = fmaf(x[t][7], a1.w, dist);
            const bool lt = dist < bestd[t];
            bestd[t] = lt ? dist : bestd[t];
            besti[t] = lt ? code : besti[t];
        }
        a0 = b0; a1 = b1;
    }

    // ---- cross-lane argmin per tuple (tie -> smaller index == numpy) ----
    float myd = 0.0f;
    int   myidx = 0;
    #pragma unroll
    for (int t = 0; t < TPW; ++t) {
        float d = bestd[t];
        int   i = besti[t];
        #pragma unroll
        for (int m = 32; m >= 1; m >>= 1) {
            const float od = __shfl_xor(d, m, 64);
            const int   oi = __shfl_xor(i, m, 64);
            if (od < d || (od == d && oi < i)) { d = od; i = oi; }
        }
        if (lane == t) { myd = d; myidx = i; }
    }

    // ---- cross-group combine via LDS ----
    if (lane < TPW) { dL[wave][lane] = myd; iL[wave][lane] = myidx; }
    __syncthreads();

    if (g == 0 && lane < TPW) {
        const float d0 = dL[wave][lane];
        const float d1 = dL[wave + 4][lane];
        // group 1 codes all larger; exact tie keeps group 0 (numpy tie-break)
        const int idx = (d1 < d0) ? iL[wave + 4][lane] : iL[wave][lane];

        const int tg = q * 32 + s * TPW + lane;   // tuple = b*16 + n
        const int b = tg >> 4, n = tg & 15;
        const float4* vr = (const float4*)(values + ((size_t)c * K_CODES + idx) * D_CB);
        const float4 v0 = vr[0];
        const float4 v1 = vr[1];
        float* op = out + (size_t)b * 32768 + c * 128 + n;
        op[0]   = v0.x; op[16]  = v0.y; op[32]  = v0.z; op[48]  = v0.w;
        op[64]  = v1.x; op[80]  = v1.y; op[96]  = v1.z; op[112] = v1.w;
    }
}

extern "C" void kernel_launch(void* const* d_in, const int* in_sizes, int n_in,
                              void* d_out, int out_size, void* d_ws, size_t ws_size,
                              hipStream_t stream) {
    const float* emb    = (const float*)d_in[0];
    const float* keys   = (const float*)d_in[1];
    const float* values = (const float*)d_in[2];
    float* out = (float*)d_out;
    dkvb_kernel<<<4 * C_NUM, THREADS, 0, stream>>>(emb, keys, values, out);
}

// Round 8
// 48.927 us; speedup vs baseline: 8.3597x; 8.3597x over previous
//
#include <hip/hip_runtime.h>

#define C_NUM   256
#define K_CODES 4096
#define D_CB    8
#define THREADS 512
#define TPW     8                   // tuples per wave
#define CHUNKS  32                  // per wave: 2048 codes / 64 lanes

__device__ __forceinline__ float rfl(float v) {
    return __int_as_float(__builtin_amdgcn_readfirstlane(__float_as_int(v)));
}

__global__ __launch_bounds__(THREADS, 2)   // min-waves=2: keeps allocator sane (R3/R4/R7 lesson)
void dkvb_kernel(const float* __restrict__ emb,
                 const float* __restrict__ keys,
                 const float* __restrict__ values,
                 float* __restrict__ out) {
    __shared__ float xs[32][D_CB];   // 1 KB
    __shared__ float dL[8][TPW];
    __shared__ int   iL[8][TPW];

    const int bid  = blockIdx.x;
    const int c    = bid & 255;      // codebook (grid 1024: 4 blocks/codebook, same XCD)
    const int q    = bid >> 8;       // tuple quarter: tuples q*32 .. q*32+31
    const int tid  = threadIdx.x;
    const int wave = tid >> 6;
    const int lane = tid & 63;
    const int s    = wave & 3;       // tuple slice (8 tuples)
    const int g    = wave >> 2;      // code half: 0 -> 0..2047, 1 -> 2048..4095

    // ---- stage this block's 32 tuples of x into LDS ----
    // x[t][j] = emb[(t>>4)*32768 + c*128 + j*16 + (t&15)]
    if (tid < 256) {
        const int tl = tid >> 3, j = tid & 7;
        const int tg = q * 32 + tl;
        xs[tl][j] = emb[(size_t)(tg >> 4) * 32768 + c * 128 + j * 16 + (tg & 15)];
    }
    __syncthreads();

    // ---- x' = -2*x into SGPRs (wave-uniform, exact scale) ----
    float x[TPW][8];
    #pragma unroll
    for (int t = 0; t < TPW; ++t) {
        #pragma unroll
        for (int j = 0; j < 8; ++j) x[t][j] = rfl(-2.0f * xs[s * TPW + t][j]);
    }

    float bestd[TPW];
    int   besti[TPW];
    #pragma unroll
    for (int t = 0; t < TPW; ++t) { bestd[t] = 3.4028235e38f; besti[t] = 0; }

    // ---- scan this group's 2048 codes; dist' = k2 + sum x'_j k_j ----
    const float4* kb = (const float4*)(keys + (size_t)c * K_CODES * D_CB);
    const int basef4 = g * 4096;     // float4 index of code-half base
    float4 a0 = kb[basef4 + lane * 2];
    float4 a1 = kb[basef4 + lane * 2 + 1];
    for (int ch = 0; ch < CHUNKS; ++ch) {
        const int nc = (ch + 1 < CHUNKS) ? (ch + 1) : ch;
        const float4 b0 = kb[basef4 + nc * 128 + lane * 2];
        const float4 b1 = kb[basef4 + nc * 128 + lane * 2 + 1];

        const int code = g * 2048 + ch * 64 + lane;
        float k2 = a0.x * a0.x;
        k2 = fmaf(a0.y, a0.y, k2);
        k2 = fmaf(a0.z, a0.z, k2);
        k2 = fmaf(a0.w, a0.w, k2);
        k2 = fmaf(a1.x, a1.x, k2);
        k2 = fmaf(a1.y, a1.y, k2);
        k2 = fmaf(a1.z, a1.z, k2);
        k2 = fmaf(a1.w, a1.w, k2);

        #pragma unroll
        for (int t = 0; t < TPW; ++t) {
            float dist = fmaf(x[t][0], a0.x, k2);
            dist = fmaf(x[t][1], a0.y, dist);
            dist = fmaf(x[t][2], a0.z, dist);
            dist = fmaf(x[t][3], a0.w, dist);
            dist = fmaf(x[t][4], a1.x, dist);
            dist = fmaf(x[t][5], a1.y, dist);
            dist = fmaf(x[t][6], a1.z, dist);
            dist = fmaf(x[t][7], a1.w, dist);
            const bool lt = dist < bestd[t];
            bestd[t] = lt ? dist : bestd[t];
            besti[t] = lt ? code : besti[t];
        }
        a0 = b0; a1 = b1;
    }

    // ---- cross-lane argmin per tuple (tie -> smaller index == numpy) ----
    float myd = 0.0f;
    int   myidx = 0;
    #pragma unroll
    for (int t = 0; t < TPW; ++t) {
        float d = bestd[t];
        int   i = besti[t];
        #pragma unroll
        for (int m = 32; m >= 1; m >>= 1) {
            const float od = __shfl_xor(d, m, 64);
            const int   oi = __shfl_xor(i, m, 64);
            if (od < d || (od == d && oi < i)) { d = od; i = oi; }
        }
        if (lane == t) { myd = d; myidx = i; }
    }

    // ---- cross-group combine via LDS ----
    if (lane < TPW) { dL[wave][lane] = myd; iL[wave][lane] = myidx; }
    __syncthreads();

    if (g == 0 && lane < TPW) {
        const float d0 = dL[wave][lane];
        const float d1 = dL[wave + 4][lane];
        // group 1 codes all larger; exact tie keeps group 0 (numpy tie-break)
        const int idx = (d1 < d0) ? iL[wave + 4][lane] : iL[wave][lane];

        const int tg = q * 32 + s * TPW + lane;   // tuple = b*16 + n
        const int b = tg >> 4, n = tg & 15;
        const float4* vr = (const float4*)(values + ((size_t)c * K_CODES + idx) * D_CB);
        const float4 v0 = vr[0];
        const float4 v1 = vr[1];
        float* op = out + (size_t)b * 32768 + c * 128 + n;
        op[0]   = v0.x; op[16]  = v0.y; op[32]  = v0.z; op[48]  = v0.w;
        op[64]  = v1.x; op[80]  = v1.y; op[96]  = v1.z; op[112] = v1.w;
    }
}

extern "C" void kernel_launch(void* const* d_in, const int* in_sizes, int n_in,
                              void* d_out, int out_size, void* d_ws, size_t ws_size,
                              hipStream_t stream) {
    const float* emb    = (const float*)d_in[0];
    const float* keys   = (const float*)d_in[1];
    const float* values = (const float*)d_in[2];
    float* out = (float*)d_out;
    dkvb_kernel<<<4 * C_NUM, THREADS, 0, stream>>>(emb, keys, values, out);
}